// Round 14
// baseline (166.560 us; speedup 1.0000x reference)
//
#include <hip/hip_runtime.h>
#include <stdint.h>

// y[b,o,w] = relu(bias[o] + sum_{i,kh} W[o,i,kh] * x[b,i,kh,w])
// q=i&3 split: q<2 ("rep") -> pre-sum W over tt => K=512; q>=2 ("pos") keeps
// the gathered K=8192. Gather fused into GEMM staging from f1t[row][q][w][kh]
// (2MB, L2-resident). r14 = r12 verbatim (best passing, 161.4us): r13's
// cooperative single-dispatch fusion silently no-ops under graph capture
// (output never written) — reverted. 3 dispatches: prep -> gemm -> finalize.

#define NDIM 1024
#define TK   16
#define KPOS 8192    // pos K: 512 i's * 16 kh
#define KREP 512     // rep K: 32 (nl,q) * 16 kh
#define NCOL 2048    // 64 batches * 32 width

typedef unsigned short u16;
typedef uint32_t u32;
typedef u16   u16x8  __attribute__((ext_vector_type(8)));
typedef __bf16 bf16x8 __attribute__((ext_vector_type(8)));
typedef float  f32x4  __attribute__((ext_vector_type(4)));

__device__ __forceinline__ u16 f2bf(float x) {
    union { float f; unsigned u; } v; v.f = x;
    unsigned r = 0x7FFFu + ((v.u >> 16) & 1u);   // round-to-nearest-even
    return (u16)((v.u + r) >> 16);
}

// async global->LDS, 16B/lane; LDS dest is wave-uniform base + lane*16
__device__ __forceinline__ void load_lds_16B(const u16* g, u16* l) {
    __builtin_amdgcn_global_load_lds(
        (__attribute__((address_space(1))) void*)(uintptr_t)g,
        (__attribute__((address_space(3))) void*)(unsigned)(uintptr_t)l,
        16, 0, 0);
}

// ---------------------------------------------------------------------------
// Kernel 1 (fused, grid-partitioned):
//   [0,256):      top-16 per row (wave/row, registers, exact fp32)
//   [256,768):    zero d_out (512 blocks x 16KB)
//   [768,1792):   W-path, one block per o:
//                   pos: Wb[o][v] = bf16(W[o][(v>>5)*64+32+(v&31)]) — the pos
//                        half of a W row is a contiguous permutation; both
//                        sides coalesced
//                   rep: W1b[o][kr] = bf16(sum_tt W[o][nl*1024+tt*64+e])
//   [1792,2048):  f1t[row][q][w][kh^swp] = bf16(f1[row, q*512+kh*32+w]),
//                 swp = 8*((w>>2)&1)  (bank/align half-swap for B reads)
// ---------------------------------------------------------------------------
#define PREP_TOPK 256
#define PREP_ZERO 512
#define PREP_W    1024
#define PREP_F1T  256

__global__ __launch_bounds__(256) void prep_kernel(const float* __restrict__ f1,
                                                   const float* __restrict__ W,
                                                   int* __restrict__ idx,
                                                   u16* __restrict__ Wb,
                                                   u16* __restrict__ W1b,
                                                   u16* __restrict__ f1t,
                                                   float* __restrict__ out) {
    const int bid = blockIdx.x;
    const int t = threadIdx.x;
    if (bid < PREP_TOPK) {
        // ---- top-16 ----
        const int lane = t & 63;
        const int row  = bid * 4 + (t >> 6);
        float v[16];
        const float* src = f1 + row * NDIM + lane;
        #pragma unroll
        for (int j = 0; j < 16; ++j) v[j] = src[j * 64];
        for (int sel = 0; sel < TK; ++sel) {
            float best = -3.402823466e38f; int bg = 0x7fffffff;
            #pragma unroll
            for (int j = 0; j < 16; ++j)
                if (v[j] > best) { best = v[j]; bg = j * 64 + lane; }
            #pragma unroll
            for (int s = 1; s < 64; s <<= 1) {
                float ov = __shfl_xor(best, s);
                int   og = __shfl_xor(bg, s);
                if (ov > best || (ov == best && og < bg)) { best = ov; bg = og; }
            }
            if (lane == sel) idx[row * TK + sel] = bg;
            #pragma unroll
            for (int j = 0; j < 16; ++j)
                if (bg == j * 64 + lane) v[j] = -3.402823466e38f;
        }
    } else if (bid < PREP_TOPK + PREP_ZERO) {
        // ---- zero the 8MB output accumulator ----
        const int zb = bid - PREP_TOPK;
        f32x4 z = {0.f, 0.f, 0.f, 0.f};
        float* p = out + (size_t)zb * 4096 + t * 16;
        #pragma unroll
        for (int j = 0; j < 4; ++j) *(f32x4*)(p + j * 4) = z;
    } else if (bid < PREP_TOPK + PREP_ZERO + PREP_W) {
        // ---- W-path: one block per output row o ----
        const int o = bid - PREP_TOPK - PREP_ZERO;   // 0..1023
        const float* wrow = W + (size_t)o * 16384;
        u16* wbrow = Wb + (size_t)o * KPOS;
        // pos half: contiguous permutation, coalesced read+write
        #pragma unroll
        for (int j = 0; j < 4; ++j) {
            const int v = j * 2048 + t * 8;              // pos-flat index
            const int u = ((v >> 5) << 6) + 32 + (v & 31);
            float4 a = *(const float4*)(wrow + u);
            float4 b = *(const float4*)(wrow + u + 4);
            u16x8 ov;
            ov[0] = f2bf(a.x); ov[1] = f2bf(a.y); ov[2] = f2bf(a.z); ov[3] = f2bf(a.w);
            ov[4] = f2bf(b.x); ov[5] = f2bf(b.y); ov[6] = f2bf(b.z); ov[7] = f2bf(b.w);
            *(u16x8*)(wbrow + v) = ov;
        }
        // rep half: reduce over tt (same mapping/order as r8 -> identical bits)
        #pragma unroll
        for (int h = 0; h < 2; ++h) {
            const int kr = h * 256 + t;        // 0..511
            const int nl = kr >> 5, e = kr & 31;
            const float* base = wrow + nl * 1024 + e;
            float s = 0.f;
            #pragma unroll
            for (int tt = 0; tt < 16; ++tt) s += base[tt * 64];
            W1b[o * KREP + kr] = f2bf(s);
        }
    } else {
        // ---- f1 -> f1t bf16 transpose (w-major, kh half-swapped by w>>2&1) ----
        const int gb = bid - PREP_TOPK - PREP_ZERO - PREP_W;   // 0..255
        const int unit = t >> 5;               // 0..7
        const int w = t & 31;
        const int rq = gb * 8 + unit;          // 0..2047
        const int row = rq >> 1, q = rq & 1;
        const float* src = f1 + row * NDIM + q * 512;
        const int swp = ((w >> 2) & 1) * 8;
        u16 tmp[16];
        #pragma unroll
        for (int kh = 0; kh < 16; ++kh)
            tmp[kh ^ swp] = f2bf(src[kh * 32 + w]);   // coalesced per-kh across lanes
        u16* dst = f1t + ((size_t)row * 2 + q) * 512 + w * 16;
        *(u16x8*)(dst)     = *(u16x8*)(tmp);
        *(u16x8*)(dst + 8) = *(u16x8*)(tmp + 8);
    }
}

// ---------------------------------------------------------------------------
// Kernel 2: bf16 MFMA GEMM, 128x128 tile, BK=64, uniform grid of 512 blocks
// (f=m*64+u, u=(n,z); XCD = u%8). Each block: 32 pos iters (its z-quarter of
// KPOS) + 2 rep iters (its z-quarter of KREP) -> 4 contributions per tile.
// A: LDS double-buffer via global_load_lds (row&7 chunk XOR swizzle), ONE
// barrier/iter. B: per-wave DMA from f1t (rows via idxL broadcast for pos,
// arithmetic for rep). Atomic scatter epilogue.
// ---------------------------------------------------------------------------
#define BM 128
#define BN 128
#define BK 64
#define KITERS 34

__global__ __launch_bounds__(256, 2) void gemm_kernel(const u16* __restrict__ Ap,
                                                      const u16* __restrict__ A1,
                                                      const u16* __restrict__ f1t,
                                                      const int* __restrict__ idx,
                                                      float* __restrict__ out) {
    __shared__ __align__(16) u16 As[2][BM * BK];   // 2x16KB, [row][chunk^(row&7)]
    __shared__ __align__(16) u16 Bs[2][16 * 512];  // 2x16KB, [ci][bloc][w][half]
    __shared__ int idxL[256];                       // [bl][nlz][tt]
    const int f = blockIdx.x;            // 0..511
    const int m = f >> 6;
    const int u = f & 63;
    const int n = u & 15;
    const int z = u >> 4;
    const int t    = threadIdx.x;
    const int lane = t & 63;
    const int wave = t >> 6;             // 0..3 == B-staging ci
    const int wm   = (wave >> 1) * 64;
    const int wn   = (wave & 1) * 64;
    const int quad = lane >> 4;
    const int l16  = lane & 15;
    const int sw   = l16 & 7;            // A-read chunk XOR key
    const int o0 = m * BM;
    const int n0 = n * BN;
    const int nb0 = n * 4;               // first batch of this tile
    const int kb = z * 2048;             // pos k-offset
    const int nl0 = z * 4;

    // preload this block's idx slice: idxL[bl*64 + nlz*16 + tt]
    {
        const int bl = t >> 6, nlz = (t >> 4) & 3, tt = t & 15;
        idxL[t] = idx[((nb0 + bl) * 16 + nl0 + nlz) * TK + tt];
    }

    f32x4 acc[4][4] = {};

    // A staging addresses: slot (row=32c+rA, chunk c8) holds chunk c8^(rA&7)
    const int rA = t >> 3;               // 0..31
    const int c8 = t & 7;
    const int csw = (c8 ^ (rA & 7)) * 8;
    const u16* gApos = Ap + (size_t)(o0 + rA) * KPOS + kb + csw;
    const u16* gArep = A1 + (size_t)(o0 + rA) * KREP + z * 128 + csw;
    const int ipbp = kb >> 4;            // z*128
    const int ipbr = z * 8;

    // stage iteration `it` into buffer `nb`: it<32 = pos, it in {32,33} = rep
    auto stage = [&](int it, int nb) {
        u16* lA = As[nb] + t * 8;
        int rows[4], qp;
        if (it < 32) {
            const int k0 = it * BK;
            #pragma unroll
            for (int c = 0; c < 4; ++c)
                load_lds_16B(gApos + (size_t)(c * 32) * KPOS + k0, lA + c * 2048);
            const int ip = ipbp + it * 4 + wave;
            qp = ip & 1;
            const int nlz = (ip >> 5) & 3, tt = (ip >> 1) & 15;
            #pragma unroll
            for (int bl = 0; bl < 4; ++bl)
                rows[bl] = idxL[bl * 64 + nlz * 16 + tt];
        } else {
            const int k0 = (it - 32) * BK;
            #pragma unroll
            for (int c = 0; c < 4; ++c)
                load_lds_16B(gArep + (size_t)(c * 32) * KREP + k0, lA + c * 2048);
            const int ip = ipbr + (it - 32) * 4 + wave;
            qp = ip & 1;
            const int nlr = ip >> 1;
            #pragma unroll
            for (int bl = 0; bl < 4; ++bl)
                rows[bl] = (nb0 + bl) * 16 + nlr;
        }
        #pragma unroll
        for (int bl = 0; bl < 4; ++bl)
            load_lds_16B(f1t + ((size_t)rows[bl] * 2 + qp) * 512 + lane * 8,
                         Bs[nb] + (wave * 4 + bl) * 512);
    };

    __syncthreads();        // idxL visible before first stage reads it
    stage(0, 0);
    __syncthreads();        // drain prologue DMA

    for (int it = 0; it < KITERS; ++it) {
        const int cur = it & 1;
        if (it + 1 < KITERS) stage(it + 1, 1 - cur);

        #pragma unroll
        for (int ks = 0; ks < 2; ++ks) {
            bf16x8 af[4], bfr[4];
            #pragma unroll
            for (int mt = 0; mt < 4; ++mt) {
                u16x8 bits = *(const u16x8*)(As[cur] + (wm + mt * 16 + l16) * BK
                                                + (((ks * 4 + quad) ^ sw) * 8));
                af[mt] = __builtin_bit_cast(bf16x8, bits);
            }
            const int ci2 = ks * 2 + (quad >> 1);
            const int qh  = quad & 1;
            #pragma unroll
            for (int nt = 0; nt < 4; ++nt) {
                const int nn = wn + nt * 16 + l16;
                const int blocf = nn >> 5, w = nn & 31;
                u16x8 bits = *(const u16x8*)(Bs[cur] + (ci2 * 4 + blocf) * 512 + w * 16
                                                + ((qh ^ ((w >> 2) & 1)) * 8));
                bfr[nt] = __builtin_bit_cast(bf16x8, bits);
            }
            #pragma unroll
            for (int mt = 0; mt < 4; ++mt)
                #pragma unroll
                for (int nt = 0; nt < 4; ++nt)
                    acc[mt][nt] = __builtin_amdgcn_mfma_f32_16x16x32_bf16(
                        af[mt], bfr[nt], acc[mt][nt], 0, 0, 0);
        }
        __syncthreads();    // one barrier per iter: releases buf[cur] AND
                            // drains the it+1 DMAs (vmcnt(0))
    }

    // epilogue: C/D row=quad*4+reg, col=l16; atomic-accumulate at final
    // scattered position: out[(b*16+(o>>6))*2048 + (o&63)*32 + w]
    #pragma unroll
    for (int nt = 0; nt < 4; ++nt) {
        const int nn = n0 + wn + nt * 16 + l16;
        const int bb = nn >> 5, w = nn & 31;
        #pragma unroll
        for (int mt = 0; mt < 4; ++mt) {
            #pragma unroll
            for (int r = 0; r < 4; ++r) {
                const int o = o0 + wm + mt * 16 + quad * 4 + r;
                unsafeAtomicAdd(out + (size_t)(bb * 16 + (o >> 6)) * 2048
                                    + (o & 63) * 32 + w,
                                acc[mt][nt][r]);
            }
        }
    }
}

// ---------------------------------------------------------------------------
// Kernel 3: in-place bias + relu on the accumulated output.
// ---------------------------------------------------------------------------
__global__ __launch_bounds__(256) void finalize_kernel(float* __restrict__ out,
                                                       const float* __restrict__ bias) {
    const int tid = blockIdx.x * 256 + threadIdx.x;
    const int f = tid * 4;
    const int o = ((f >> 11) & 15) * 64 + ((f & 2047) >> 5);
    const float bv = bias[o];
    float4 x = *(float4*)(out + f);
    x.x = fmaxf(x.x + bv, 0.f);
    x.y = fmaxf(x.y + bv, 0.f);
    x.z = fmaxf(x.z + bv, 0.f);
    x.w = fmaxf(x.w + bv, 0.f);
    *(float4*)(out + f) = x;
}

// ---------------------------------------------------------------------------
extern "C" void kernel_launch(void* const* d_in, const int* in_sizes, int n_in,
                              void* d_out, int out_size, void* d_ws, size_t ws_size,
                              hipStream_t stream) {
    const float* f1   = (const float*)d_in[0];   // [1024][1024]
    const float* Wc   = (const float*)d_in[1];   // [1024][1024][16][1]
    const float* bias = (const float*)d_in[2];   // [1024]
    float* out = (float*)d_out;                  // [1024][2048]

    // workspace layout (bytes):
    //   idx:  0         (64KB)
    //   Wb:   65536     (1024*8192*2 = 16MB)
    //   W1b:  16842752  (1024*512*2  = 1MB)
    //   f1t:  17891328  (1024*2*512*2 = 2MB)
    int* idx = (int*)d_ws;
    u16* Wb  = (u16*)((char*)d_ws + 65536);
    u16* W1b = (u16*)((char*)d_ws + 16842752);
    u16* f1t = (u16*)((char*)d_ws + 17891328);

    prep_kernel<<<PREP_TOPK + PREP_ZERO + PREP_W + PREP_F1T,
                  256, 0, stream>>>(f1, Wc, idx, Wb, W1b, f1t, out);
    gemm_kernel<<<512, 256, 0, stream>>>(Wb, W1b, f1t, idx, out);
    finalize_kernel<<<(NDIM * NCOL) / (4 * 256), 256, 0, stream>>>(out, bias);
}

// Round 15
// 166.446 us; speedup vs baseline: 1.0007x; 1.0007x over previous
//
#include <hip/hip_runtime.h>
#include <stdint.h>

// y[b,o,w] = relu(bias[o] + sum_{i,kh} W[o,i,kh] * x[b,i,kh,w])
// q=i&3 split: q<2 ("rep") -> pre-sum W over tt => K=512; q>=2 ("pos") keeps
// the gathered K=8192. Gather fused into GEMM staging from f1t[row][q][w][kh]
// (2MB, L2-resident). r15 = r12 with the GEMM compute core swapped to
// v_mfma_f32_32x32x16_bf16 (half the MFMA issues, ~20% more FLOP/cyc on the
// matrix pipe); staging, swizzles, prep, finalize all byte-identical.
// 3 dispatches: prep -> gemm -> finalize.

#define NDIM 1024
#define TK   16
#define KPOS 8192    // pos K: 512 i's * 16 kh
#define KREP 512     // rep K: 32 (nl,q) * 16 kh
#define NCOL 2048    // 64 batches * 32 width

typedef unsigned short u16;
typedef uint32_t u32;
typedef u16   u16x8  __attribute__((ext_vector_type(8)));
typedef __bf16 bf16x8 __attribute__((ext_vector_type(8)));
typedef float  f32x4  __attribute__((ext_vector_type(4)));
typedef float  f32x16 __attribute__((ext_vector_type(16)));

__device__ __forceinline__ u16 f2bf(float x) {
    union { float f; unsigned u; } v; v.f = x;
    unsigned r = 0x7FFFu + ((v.u >> 16) & 1u);   // round-to-nearest-even
    return (u16)((v.u + r) >> 16);
}

// async global->LDS, 16B/lane; LDS dest is wave-uniform base + lane*16
__device__ __forceinline__ void load_lds_16B(const u16* g, u16* l) {
    __builtin_amdgcn_global_load_lds(
        (__attribute__((address_space(1))) void*)(uintptr_t)g,
        (__attribute__((address_space(3))) void*)(unsigned)(uintptr_t)l,
        16, 0, 0);
}

// ---------------------------------------------------------------------------
// Kernel 1 (fused, grid-partitioned) — identical to r12:
//   [0,256):      top-16 per row (wave/row, registers, exact fp32)
//   [256,768):    zero d_out (512 blocks x 16KB)
//   [768,1792):   W-path, one block per o:
//                   pos: Wb[o][v] = bf16(W[o][(v>>5)*64+32+(v&31)])
//                   rep: W1b[o][kr] = bf16(sum_tt W[o][nl*1024+tt*64+e])
//   [1792,2048):  f1t[row][q][w][kh^swp] = bf16(f1[row, q*512+kh*32+w]),
//                 swp = 8*((w>>2)&1)
// ---------------------------------------------------------------------------
#define PREP_TOPK 256
#define PREP_ZERO 512
#define PREP_W    1024
#define PREP_F1T  256

__global__ __launch_bounds__(256) void prep_kernel(const float* __restrict__ f1,
                                                   const float* __restrict__ W,
                                                   int* __restrict__ idx,
                                                   u16* __restrict__ Wb,
                                                   u16* __restrict__ W1b,
                                                   u16* __restrict__ f1t,
                                                   float* __restrict__ out) {
    const int bid = blockIdx.x;
    const int t = threadIdx.x;
    if (bid < PREP_TOPK) {
        // ---- top-16 ----
        const int lane = t & 63;
        const int row  = bid * 4 + (t >> 6);
        float v[16];
        const float* src = f1 + row * NDIM + lane;
        #pragma unroll
        for (int j = 0; j < 16; ++j) v[j] = src[j * 64];
        for (int sel = 0; sel < TK; ++sel) {
            float best = -3.402823466e38f; int bg = 0x7fffffff;
            #pragma unroll
            for (int j = 0; j < 16; ++j)
                if (v[j] > best) { best = v[j]; bg = j * 64 + lane; }
            #pragma unroll
            for (int s = 1; s < 64; s <<= 1) {
                float ov = __shfl_xor(best, s);
                int   og = __shfl_xor(bg, s);
                if (ov > best || (ov == best && og < bg)) { best = ov; bg = og; }
            }
            if (lane == sel) idx[row * TK + sel] = bg;
            #pragma unroll
            for (int j = 0; j < 16; ++j)
                if (bg == j * 64 + lane) v[j] = -3.402823466e38f;
        }
    } else if (bid < PREP_TOPK + PREP_ZERO) {
        // ---- zero the 8MB output accumulator ----
        const int zb = bid - PREP_TOPK;
        f32x4 z = {0.f, 0.f, 0.f, 0.f};
        float* p = out + (size_t)zb * 4096 + t * 16;
        #pragma unroll
        for (int j = 0; j < 4; ++j) *(f32x4*)(p + j * 4) = z;
    } else if (bid < PREP_TOPK + PREP_ZERO + PREP_W) {
        // ---- W-path: one block per output row o ----
        const int o = bid - PREP_TOPK - PREP_ZERO;   // 0..1023
        const float* wrow = W + (size_t)o * 16384;
        u16* wbrow = Wb + (size_t)o * KPOS;
        // pos half: contiguous permutation, coalesced read+write
        #pragma unroll
        for (int j = 0; j < 4; ++j) {
            const int v = j * 2048 + t * 8;              // pos-flat index
            const int u = ((v >> 5) << 6) + 32 + (v & 31);
            float4 a = *(const float4*)(wrow + u);
            float4 b = *(const float4*)(wrow + u + 4);
            u16x8 ov;
            ov[0] = f2bf(a.x); ov[1] = f2bf(a.y); ov[2] = f2bf(a.z); ov[3] = f2bf(a.w);
            ov[4] = f2bf(b.x); ov[5] = f2bf(b.y); ov[6] = f2bf(b.z); ov[7] = f2bf(b.w);
            *(u16x8*)(wbrow + v) = ov;
        }
        // rep half: reduce over tt
        #pragma unroll
        for (int h = 0; h < 2; ++h) {
            const int kr = h * 256 + t;        // 0..511
            const int nl = kr >> 5, e = kr & 31;
            const float* base = wrow + nl * 1024 + e;
            float s = 0.f;
            #pragma unroll
            for (int tt = 0; tt < 16; ++tt) s += base[tt * 64];
            W1b[o * KREP + kr] = f2bf(s);
        }
    } else {
        // ---- f1 -> f1t bf16 transpose (w-major, kh half-swapped by w>>2&1) ----
        const int gb = bid - PREP_TOPK - PREP_ZERO - PREP_W;   // 0..255
        const int unit = t >> 5;               // 0..7
        const int w = t & 31;
        const int rq = gb * 8 + unit;          // 0..2047
        const int row = rq >> 1, q = rq & 1;
        const float* src = f1 + row * NDIM + q * 512;
        const int swp = ((w >> 2) & 1) * 8;
        u16 tmp[16];
        #pragma unroll
        for (int kh = 0; kh < 16; ++kh)
            tmp[kh ^ swp] = f2bf(src[kh * 32 + w]);   // coalesced per-kh across lanes
        u16* dst = f1t + ((size_t)row * 2 + q) * 512 + w * 16;
        *(u16x8*)(dst)     = *(u16x8*)(tmp);
        *(u16x8*)(dst + 8) = *(u16x8*)(tmp + 8);
    }
}

// ---------------------------------------------------------------------------
// Kernel 2: bf16 MFMA GEMM, 128x128 tile, BK=64, uniform grid of 512 blocks
// (f=m*64+u, u=(n,z); XCD = u%8). 32 pos iters + 2 rep iters per block.
// A: LDS double-buffer via global_load_lds (row&7 chunk XOR swizzle), ONE
// barrier/iter. B: per-wave DMA from f1t. Compute: 32x32x16 MFMA, wave tile
// 64x64 = 2x2 of 32x32; A[m=lane&31][k=(lane>>5)*8+j], B likewise; C/D
// row=(reg&3)+8*(reg>>2)+4*(lane>>5), col=lane&31 (m74/m101-verified).
// Atomic scatter epilogue.
// ---------------------------------------------------------------------------
#define BM 128
#define BN 128
#define BK 64
#define KITERS 34

__global__ __launch_bounds__(256, 2) void gemm_kernel(const u16* __restrict__ Ap,
                                                      const u16* __restrict__ A1,
                                                      const u16* __restrict__ f1t,
                                                      const int* __restrict__ idx,
                                                      float* __restrict__ out) {
    __shared__ __align__(16) u16 As[2][BM * BK];   // 2x16KB, [row][chunk^(row&7)]
    __shared__ __align__(16) u16 Bs[2][16 * 512];  // 2x16KB, [ci][bloc][w][half]
    __shared__ int idxL[256];                       // [bl][nlz][tt]
    const int f = blockIdx.x;            // 0..511
    const int m = f >> 6;
    const int u = f & 63;
    const int n = u & 15;
    const int z = u >> 4;
    const int t    = threadIdx.x;
    const int lane = t & 63;
    const int wave = t >> 6;             // 0..3 == B-staging ci
    const int wm   = (wave >> 1) * 64;
    const int wn   = (wave & 1) * 64;
    const int l32  = lane & 31;
    const int kg   = lane >> 5;          // k-half within a 16-k step
    const int swA  = l32 & 7;            // A-read chunk XOR key (row&7)
    const int o0 = m * BM;
    const int n0 = n * BN;
    const int nb0 = n * 4;               // first batch of this tile
    const int kb = z * 2048;             // pos k-offset
    const int nl0 = z * 4;

    // preload this block's idx slice: idxL[bl*64 + nlz*16 + tt]
    {
        const int bl = t >> 6, nlz = (t >> 4) & 3, tt = t & 15;
        idxL[t] = idx[((nb0 + bl) * 16 + nl0 + nlz) * TK + tt];
    }

    f32x16 acc[2][2] = {};

    // A staging addresses: slot (row=32c+rA, chunk c8) holds chunk c8^(rA&7)
    const int rA = t >> 3;               // 0..31
    const int c8 = t & 7;
    const int csw = (c8 ^ (rA & 7)) * 8;
    const u16* gApos = Ap + (size_t)(o0 + rA) * KPOS + kb + csw;
    const u16* gArep = A1 + (size_t)(o0 + rA) * KREP + z * 128 + csw;
    const int ipbp = kb >> 4;            // z*128
    const int ipbr = z * 8;

    // stage iteration `it` into buffer `nb`: it<32 = pos, it in {32,33} = rep
    auto stage = [&](int it, int nb) {
        u16* lA = As[nb] + t * 8;
        int rows[4], qp;
        if (it < 32) {
            const int k0 = it * BK;
            #pragma unroll
            for (int c = 0; c < 4; ++c)
                load_lds_16B(gApos + (size_t)(c * 32) * KPOS + k0, lA + c * 2048);
            const int ip = ipbp + it * 4 + wave;
            qp = ip & 1;
            const int nlz = (ip >> 5) & 3, tt = (ip >> 1) & 15;
            #pragma unroll
            for (int bl = 0; bl < 4; ++bl)
                rows[bl] = idxL[bl * 64 + nlz * 16 + tt];
        } else {
            const int k0 = (it - 32) * BK;
            #pragma unroll
            for (int c = 0; c < 4; ++c)
                load_lds_16B(gArep + (size_t)(c * 32) * KREP + k0, lA + c * 2048);
            const int ip = ipbr + (it - 32) * 4 + wave;
            qp = ip & 1;
            const int nlr = ip >> 1;
            #pragma unroll
            for (int bl = 0; bl < 4; ++bl)
                rows[bl] = (nb0 + bl) * 16 + nlr;
        }
        #pragma unroll
        for (int bl = 0; bl < 4; ++bl)
            load_lds_16B(f1t + ((size_t)rows[bl] * 2 + qp) * 512 + lane * 8,
                         Bs[nb] + (wave * 4 + bl) * 512);
    };

    __syncthreads();        // idxL visible before first stage reads it
    stage(0, 0);
    __syncthreads();        // drain prologue DMA

    for (int it = 0; it < KITERS; ++it) {
        const int cur = it & 1;
        if (it + 1 < KITERS) stage(it + 1, 1 - cur);

        // 4 k-steps of 16 per BK=64 iter; k-step s == staged i' index s
        #pragma unroll
        for (int s = 0; s < 4; ++s) {
            bf16x8 af[2], bfr[2];
            #pragma unroll
            for (int mt = 0; mt < 2; ++mt) {
                u16x8 bits = *(const u16x8*)(As[cur] + (wm + mt * 32 + l32) * BK
                                                + (((s * 2 + kg) ^ swA) * 8));
                af[mt] = __builtin_bit_cast(bf16x8, bits);
            }
            #pragma unroll
            for (int nt = 0; nt < 2; ++nt) {
                const int bloc = (wn >> 5) + nt;           // 0..3
                const int w = l32;
                u16x8 bits = *(const u16x8*)(Bs[cur] + (s * 4 + bloc) * 512 + w * 16
                                                + ((kg ^ ((w >> 2) & 1)) * 8));
                bfr[nt] = __builtin_bit_cast(bf16x8, bits);
            }
            #pragma unroll
            for (int mt = 0; mt < 2; ++mt)
                #pragma unroll
                for (int nt = 0; nt < 2; ++nt)
                    acc[mt][nt] = __builtin_amdgcn_mfma_f32_32x32x16_bf16(
                        af[mt], bfr[nt], acc[mt][nt], 0, 0, 0);
        }
        __syncthreads();    // one barrier per iter: releases buf[cur] AND
                            // drains the it+1 DMAs (vmcnt(0))
    }

    // epilogue: C/D col=lane&31, row=(reg&3)+8*(reg>>2)+4*kg; atomic scatter
    // to out[(b*16+(o>>6))*2048 + (o&63)*32 + w]
    #pragma unroll
    for (int nt = 0; nt < 2; ++nt) {
        const int nn = n0 + wn + nt * 32 + l32;
        const int bb = nn >> 5, w = nn & 31;
        #pragma unroll
        for (int mt = 0; mt < 2; ++mt) {
            #pragma unroll
            for (int r = 0; r < 16; ++r) {
                const int row = (r & 3) + 8 * (r >> 2) + 4 * kg;
                const int o = o0 + wm + mt * 32 + row;
                unsafeAtomicAdd(out + (size_t)(bb * 16 + (o >> 6)) * 2048
                                    + (o & 63) * 32 + w,
                                acc[mt][nt][r]);
            }
        }
    }
}

// ---------------------------------------------------------------------------
// Kernel 3: in-place bias + relu on the accumulated output.
// ---------------------------------------------------------------------------
__global__ __launch_bounds__(256) void finalize_kernel(float* __restrict__ out,
                                                       const float* __restrict__ bias) {
    const int tid = blockIdx.x * 256 + threadIdx.x;
    const int f = tid * 4;
    const int o = ((f >> 11) & 15) * 64 + ((f & 2047) >> 5);
    const float bv = bias[o];
    float4 x = *(float4*)(out + f);
    x.x = fmaxf(x.x + bv, 0.f);
    x.y = fmaxf(x.y + bv, 0.f);
    x.z = fmaxf(x.z + bv, 0.f);
    x.w = fmaxf(x.w + bv, 0.f);
    *(float4*)(out + f) = x;
}

// ---------------------------------------------------------------------------
extern "C" void kernel_launch(void* const* d_in, const int* in_sizes, int n_in,
                              void* d_out, int out_size, void* d_ws, size_t ws_size,
                              hipStream_t stream) {
    const float* f1   = (const float*)d_in[0];   // [1024][1024]
    const float* Wc   = (const float*)d_in[1];   // [1024][1024][16][1]
    const float* bias = (const float*)d_in[2];   // [1024]
    float* out = (float*)d_out;                  // [1024][2048]

    // workspace layout (bytes):
    //   idx:  0         (64KB)
    //   Wb:   65536     (1024*8192*2 = 16MB)
    //   W1b:  16842752  (1024*512*2  = 1MB)
    //   f1t:  17891328  (1024*2*512*2 = 2MB)
    int* idx = (int*)d_ws;
    u16* Wb  = (u16*)((char*)d_ws + 65536);
    u16* W1b = (u16*)((char*)d_ws + 16842752);
    u16* f1t = (u16*)((char*)d_ws + 17891328);

    prep_kernel<<<PREP_TOPK + PREP_ZERO + PREP_W + PREP_F1T,
                  256, 0, stream>>>(f1, Wc, idx, Wb, W1b, f1t, out);
    gemm_kernel<<<512, 256, 0, stream>>>(Wb, W1b, f1t, idx, out);
    finalize_kernel<<<(NDIM * NCOL) / (4 * 256), 256, 0, stream>>>(out, bias);
}

// Round 16
// 165.101 us; speedup vs baseline: 1.0088x; 1.0081x over previous
//
#include <hip/hip_runtime.h>
#include <stdint.h>

// y[b,o,w] = relu(bias[o] + sum_{i,kh} W[o,i,kh] * x[b,i,kh,w])
// q=i&3 split: q<2 ("rep") -> pre-sum W over tt => K=512; q>=2 ("pos") keeps
// the gathered K=8192. Gather fused into GEMM staging from f1t[row][q][w][kh]
// (2MB, L2-resident). r16 = r12 verbatim (best passing, 161.4us).
// Probe ledger: r15's 32x32x16 MFMA was correctness-verified but perf-neutral
// (VALUBusy -5pp, dur unchanged -> not issue-bound) and added 4.4M LDS bank
// conflicts -> reverted to the 16x16 core (0 conflicts).
// 3 dispatches: prep -> gemm -> finalize.

#define NDIM 1024
#define TK   16
#define KPOS 8192    // pos K: 512 i's * 16 kh
#define KREP 512     // rep K: 32 (nl,q) * 16 kh
#define NCOL 2048    // 64 batches * 32 width

typedef unsigned short u16;
typedef uint32_t u32;
typedef u16   u16x8  __attribute__((ext_vector_type(8)));
typedef __bf16 bf16x8 __attribute__((ext_vector_type(8)));
typedef float  f32x4  __attribute__((ext_vector_type(4)));

__device__ __forceinline__ u16 f2bf(float x) {
    union { float f; unsigned u; } v; v.f = x;
    unsigned r = 0x7FFFu + ((v.u >> 16) & 1u);   // round-to-nearest-even
    return (u16)((v.u + r) >> 16);
}

// async global->LDS, 16B/lane; LDS dest is wave-uniform base + lane*16
__device__ __forceinline__ void load_lds_16B(const u16* g, u16* l) {
    __builtin_amdgcn_global_load_lds(
        (__attribute__((address_space(1))) void*)(uintptr_t)g,
        (__attribute__((address_space(3))) void*)(unsigned)(uintptr_t)l,
        16, 0, 0);
}

// ---------------------------------------------------------------------------
// Kernel 1 (fused, grid-partitioned):
//   [0,256):      top-16 per row (wave/row, registers, exact fp32)
//   [256,768):    zero d_out (512 blocks x 16KB)
//   [768,1792):   W-path, one block per o:
//                   pos: Wb[o][v] = bf16(W[o][(v>>5)*64+32+(v&31)]) — the pos
//                        half of a W row is a contiguous permutation; both
//                        sides coalesced
//                   rep: W1b[o][kr] = bf16(sum_tt W[o][nl*1024+tt*64+e])
//   [1792,2048):  f1t[row][q][w][kh^swp] = bf16(f1[row, q*512+kh*32+w]),
//                 swp = 8*((w>>2)&1)  (bank/align half-swap for B reads)
// ---------------------------------------------------------------------------
#define PREP_TOPK 256
#define PREP_ZERO 512
#define PREP_W    1024
#define PREP_F1T  256

__global__ __launch_bounds__(256) void prep_kernel(const float* __restrict__ f1,
                                                   const float* __restrict__ W,
                                                   int* __restrict__ idx,
                                                   u16* __restrict__ Wb,
                                                   u16* __restrict__ W1b,
                                                   u16* __restrict__ f1t,
                                                   float* __restrict__ out) {
    const int bid = blockIdx.x;
    const int t = threadIdx.x;
    if (bid < PREP_TOPK) {
        // ---- top-16 ----
        const int lane = t & 63;
        const int row  = bid * 4 + (t >> 6);
        float v[16];
        const float* src = f1 + row * NDIM + lane;
        #pragma unroll
        for (int j = 0; j < 16; ++j) v[j] = src[j * 64];
        for (int sel = 0; sel < TK; ++sel) {
            float best = -3.402823466e38f; int bg = 0x7fffffff;
            #pragma unroll
            for (int j = 0; j < 16; ++j)
                if (v[j] > best) { best = v[j]; bg = j * 64 + lane; }
            #pragma unroll
            for (int s = 1; s < 64; s <<= 1) {
                float ov = __shfl_xor(best, s);
                int   og = __shfl_xor(bg, s);
                if (ov > best || (ov == best && og < bg)) { best = ov; bg = og; }
            }
            if (lane == sel) idx[row * TK + sel] = bg;
            #pragma unroll
            for (int j = 0; j < 16; ++j)
                if (bg == j * 64 + lane) v[j] = -3.402823466e38f;
        }
    } else if (bid < PREP_TOPK + PREP_ZERO) {
        // ---- zero the 8MB output accumulator ----
        const int zb = bid - PREP_TOPK;
        f32x4 z = {0.f, 0.f, 0.f, 0.f};
        float* p = out + (size_t)zb * 4096 + t * 16;
        #pragma unroll
        for (int j = 0; j < 4; ++j) *(f32x4*)(p + j * 4) = z;
    } else if (bid < PREP_TOPK + PREP_ZERO + PREP_W) {
        // ---- W-path: one block per output row o ----
        const int o = bid - PREP_TOPK - PREP_ZERO;   // 0..1023
        const float* wrow = W + (size_t)o * 16384;
        u16* wbrow = Wb + (size_t)o * KPOS;
        // pos half: contiguous permutation, coalesced read+write
        #pragma unroll
        for (int j = 0; j < 4; ++j) {
            const int v = j * 2048 + t * 8;              // pos-flat index
            const int u = ((v >> 5) << 6) + 32 + (v & 31);
            float4 a = *(const float4*)(wrow + u);
            float4 b = *(const float4*)(wrow + u + 4);
            u16x8 ov;
            ov[0] = f2bf(a.x); ov[1] = f2bf(a.y); ov[2] = f2bf(a.z); ov[3] = f2bf(a.w);
            ov[4] = f2bf(b.x); ov[5] = f2bf(b.y); ov[6] = f2bf(b.z); ov[7] = f2bf(b.w);
            *(u16x8*)(wbrow + v) = ov;
        }
        // rep half: reduce over tt
        #pragma unroll
        for (int h = 0; h < 2; ++h) {
            const int kr = h * 256 + t;        // 0..511
            const int nl = kr >> 5, e = kr & 31;
            const float* base = wrow + nl * 1024 + e;
            float s = 0.f;
            #pragma unroll
            for (int tt = 0; tt < 16; ++tt) s += base[tt * 64];
            W1b[o * KREP + kr] = f2bf(s);
        }
    } else {
        // ---- f1 -> f1t bf16 transpose (w-major, kh half-swapped by w>>2&1) ----
        const int gb = bid - PREP_TOPK - PREP_ZERO - PREP_W;   // 0..255
        const int unit = t >> 5;               // 0..7
        const int w = t & 31;
        const int rq = gb * 8 + unit;          // 0..2047
        const int row = rq >> 1, q = rq & 1;
        const float* src = f1 + row * NDIM + q * 512;
        const int swp = ((w >> 2) & 1) * 8;
        u16 tmp[16];
        #pragma unroll
        for (int kh = 0; kh < 16; ++kh)
            tmp[kh ^ swp] = f2bf(src[kh * 32 + w]);   // coalesced per-kh across lanes
        u16* dst = f1t + ((size_t)row * 2 + q) * 512 + w * 16;
        *(u16x8*)(dst)     = *(u16x8*)(tmp);
        *(u16x8*)(dst + 8) = *(u16x8*)(tmp + 8);
    }
}

// ---------------------------------------------------------------------------
// Kernel 2: bf16 MFMA GEMM, 128x128 tile, BK=64, uniform grid of 512 blocks
// (f=m*64+u, u=(n,z); XCD = u%8). Each block: 32 pos iters (its z-quarter of
// KPOS) + 2 rep iters (its z-quarter of KREP) -> 4 contributions per tile.
// A: LDS double-buffer via global_load_lds (row&7 chunk XOR swizzle), ONE
// barrier/iter. B: per-wave DMA from f1t (rows via idxL broadcast for pos,
// arithmetic for rep). 16x16x32 MFMA (conflict-free read phasing).
// Atomic scatter epilogue.
// ---------------------------------------------------------------------------
#define BM 128
#define BN 128
#define BK 64
#define KITERS 34

__global__ __launch_bounds__(256, 2) void gemm_kernel(const u16* __restrict__ Ap,
                                                      const u16* __restrict__ A1,
                                                      const u16* __restrict__ f1t,
                                                      const int* __restrict__ idx,
                                                      float* __restrict__ out) {
    __shared__ __align__(16) u16 As[2][BM * BK];   // 2x16KB, [row][chunk^(row&7)]
    __shared__ __align__(16) u16 Bs[2][16 * 512];  // 2x16KB, [ci][bloc][w][half]
    __shared__ int idxL[256];                       // [bl][nlz][tt]
    const int f = blockIdx.x;            // 0..511
    const int m = f >> 6;
    const int u = f & 63;
    const int n = u & 15;
    const int z = u >> 4;
    const int t    = threadIdx.x;
    const int lane = t & 63;
    const int wave = t >> 6;             // 0..3 == B-staging ci
    const int wm   = (wave >> 1) * 64;
    const int wn   = (wave & 1) * 64;
    const int quad = lane >> 4;
    const int l16  = lane & 15;
    const int sw   = l16 & 7;            // A-read chunk XOR key
    const int o0 = m * BM;
    const int n0 = n * BN;
    const int nb0 = n * 4;               // first batch of this tile
    const int kb = z * 2048;             // pos k-offset
    const int nl0 = z * 4;

    // preload this block's idx slice: idxL[bl*64 + nlz*16 + tt]
    {
        const int bl = t >> 6, nlz = (t >> 4) & 3, tt = t & 15;
        idxL[t] = idx[((nb0 + bl) * 16 + nl0 + nlz) * TK + tt];
    }

    f32x4 acc[4][4] = {};

    // A staging addresses: slot (row=32c+rA, chunk c8) holds chunk c8^(rA&7)
    const int rA = t >> 3;               // 0..31
    const int c8 = t & 7;
    const int csw = (c8 ^ (rA & 7)) * 8;
    const u16* gApos = Ap + (size_t)(o0 + rA) * KPOS + kb + csw;
    const u16* gArep = A1 + (size_t)(o0 + rA) * KREP + z * 128 + csw;
    const int ipbp = kb >> 4;            // z*128
    const int ipbr = z * 8;

    // stage iteration `it` into buffer `nb`: it<32 = pos, it in {32,33} = rep
    auto stage = [&](int it, int nb) {
        u16* lA = As[nb] + t * 8;
        int rows[4], qp;
        if (it < 32) {
            const int k0 = it * BK;
            #pragma unroll
            for (int c = 0; c < 4; ++c)
                load_lds_16B(gApos + (size_t)(c * 32) * KPOS + k0, lA + c * 2048);
            const int ip = ipbp + it * 4 + wave;
            qp = ip & 1;
            const int nlz = (ip >> 5) & 3, tt = (ip >> 1) & 15;
            #pragma unroll
            for (int bl = 0; bl < 4; ++bl)
                rows[bl] = idxL[bl * 64 + nlz * 16 + tt];
        } else {
            const int k0 = (it - 32) * BK;
            #pragma unroll
            for (int c = 0; c < 4; ++c)
                load_lds_16B(gArep + (size_t)(c * 32) * KREP + k0, lA + c * 2048);
            const int ip = ipbr + (it - 32) * 4 + wave;
            qp = ip & 1;
            const int nlr = ip >> 1;
            #pragma unroll
            for (int bl = 0; bl < 4; ++bl)
                rows[bl] = (nb0 + bl) * 16 + nlr;
        }
        #pragma unroll
        for (int bl = 0; bl < 4; ++bl)
            load_lds_16B(f1t + ((size_t)rows[bl] * 2 + qp) * 512 + lane * 8,
                         Bs[nb] + (wave * 4 + bl) * 512);
    };

    __syncthreads();        // idxL visible before first stage reads it
    stage(0, 0);
    __syncthreads();        // drain prologue DMA

    for (int it = 0; it < KITERS; ++it) {
        const int cur = it & 1;
        if (it + 1 < KITERS) stage(it + 1, 1 - cur);

        #pragma unroll
        for (int ks = 0; ks < 2; ++ks) {
            bf16x8 af[4], bfr[4];
            #pragma unroll
            for (int mt = 0; mt < 4; ++mt) {
                u16x8 bits = *(const u16x8*)(As[cur] + (wm + mt * 16 + l16) * BK
                                                + (((ks * 4 + quad) ^ sw) * 8));
                af[mt] = __builtin_bit_cast(bf16x8, bits);
            }
            const int ci2 = ks * 2 + (quad >> 1);
            const int qh  = quad & 1;
            #pragma unroll
            for (int nt = 0; nt < 4; ++nt) {
                const int nn = wn + nt * 16 + l16;
                const int blocf = nn >> 5, w = nn & 31;
                u16x8 bits = *(const u16x8*)(Bs[cur] + (ci2 * 4 + blocf) * 512 + w * 16
                                                + ((qh ^ ((w >> 2) & 1)) * 8));
                bfr[nt] = __builtin_bit_cast(bf16x8, bits);
            }
            #pragma unroll
            for (int mt = 0; mt < 4; ++mt)
                #pragma unroll
                for (int nt = 0; nt < 4; ++nt)
                    acc[mt][nt] = __builtin_amdgcn_mfma_f32_16x16x32_bf16(
                        af[mt], bfr[nt], acc[mt][nt], 0, 0, 0);
        }
        __syncthreads();    // one barrier per iter: releases buf[cur] AND
                            // drains the it+1 DMAs (vmcnt(0))
    }

    // epilogue: C/D row=quad*4+reg, col=l16; atomic-accumulate at final
    // scattered position: out[(b*16+(o>>6))*2048 + (o&63)*32 + w]
    #pragma unroll
    for (int nt = 0; nt < 4; ++nt) {
        const int nn = n0 + wn + nt * 16 + l16;
        const int bb = nn >> 5, w = nn & 31;
        #pragma unroll
        for (int mt = 0; mt < 4; ++mt) {
            #pragma unroll
            for (int r = 0; r < 4; ++r) {
                const int o = o0 + wm + mt * 16 + quad * 4 + r;
                unsafeAtomicAdd(out + (size_t)(bb * 16 + (o >> 6)) * 2048
                                    + (o & 63) * 32 + w,
                                acc[mt][nt][r]);
            }
        }
    }
}

// ---------------------------------------------------------------------------
// Kernel 3: in-place bias + relu on the accumulated output.
// ---------------------------------------------------------------------------
__global__ __launch_bounds__(256) void finalize_kernel(float* __restrict__ out,
                                                       const float* __restrict__ bias) {
    const int tid = blockIdx.x * 256 + threadIdx.x;
    const int f = tid * 4;
    const int o = ((f >> 11) & 15) * 64 + ((f & 2047) >> 5);
    const float bv = bias[o];
    float4 x = *(float4*)(out + f);
    x.x = fmaxf(x.x + bv, 0.f);
    x.y = fmaxf(x.y + bv, 0.f);
    x.z = fmaxf(x.z + bv, 0.f);
    x.w = fmaxf(x.w + bv, 0.f);
    *(float4*)(out + f) = x;
}

// ---------------------------------------------------------------------------
extern "C" void kernel_launch(void* const* d_in, const int* in_sizes, int n_in,
                              void* d_out, int out_size, void* d_ws, size_t ws_size,
                              hipStream_t stream) {
    const float* f1   = (const float*)d_in[0];   // [1024][1024]
    const float* Wc   = (const float*)d_in[1];   // [1024][1024][16][1]
    const float* bias = (const float*)d_in[2];   // [1024]
    float* out = (float*)d_out;                  // [1024][2048]

    // workspace layout (bytes):
    //   idx:  0         (64KB)
    //   Wb:   65536     (1024*8192*2 = 16MB)
    //   W1b:  16842752  (1024*512*2  = 1MB)
    //   f1t:  17891328  (1024*2*512*2 = 2MB)
    int* idx = (int*)d_ws;
    u16* Wb  = (u16*)((char*)d_ws + 65536);
    u16* W1b = (u16*)((char*)d_ws + 16842752);
    u16* f1t = (u16*)((char*)d_ws + 17891328);

    prep_kernel<<<PREP_TOPK + PREP_ZERO + PREP_W + PREP_F1T,
                  256, 0, stream>>>(f1, Wc, idx, Wb, W1b, f1t, out);
    gemm_kernel<<<512, 256, 0, stream>>>(Wb, W1b, f1t, idx, out);
    finalize_kernel<<<(NDIM * NCOL) / (4 * 256), 256, 0, stream>>>(out, bias);
}